// Round 8
// baseline (553.363 us; speedup 1.0000x reference)
//
#include <hip/hip_runtime.h>

// UniversalGRU: 2-layer GRU (B=2048, T=512, D=1, H=64) + FC(64->1).
// R15 = R14 (G=2 batch groups, weight-sharing, h-as-B-operand,
// tau-single split) with the R14 CORRECTNESS BUG fixed: R14 gave L1
// waves 511 in-loop barriers vs L0's 512 (loop ran t=1..512 with a
// gated barrier), shifting barrier pairing by one -- L1 read hAq while
// L0 was writing it (absmax 0.17). R15 restores the R12 barrier
// skeleton: BOTH roles loop t=0..511, EVERY iteration ends in
// __syncthreads() (L1 idles at t=0), epilogue (hB(511)+FC) after the
// loop, one final barrier. All waves: 1+512+1 = 514 barriers.
// Perf theory (unmeasured in R14): two independent 16-row groups per
// block interleave their dependency chains in the same wave's issue
// slots -> interval goes issue-bound (~1000 cyc) instead of
// latency-bound (R12: 1390 cyc vs 520 issue). 64 blocks x 512 threads.

#define T_LEN 512
#define BROWS 32
#define LOG2E 1.44269504088896f

typedef float          f32x4 __attribute__((ext_vector_type(4)));
typedef __bf16         bf16x8 __attribute__((ext_vector_type(8)));
typedef unsigned short us8   __attribute__((ext_vector_type(8)));
typedef unsigned int   ui4   __attribute__((ext_vector_type(4)));
typedef unsigned int   ui2   __attribute__((ext_vector_type(2)));
typedef unsigned short ushort_t;

__device__ __forceinline__ float bf2f(ushort_t b){
    unsigned int u = ((unsigned int)b) << 16;
    return __uint_as_float(u);
}
__device__ __forceinline__ ushort_t f2bf(float f){
    unsigned int u = __float_as_uint(f);
    u = (u + 0x7FFFu + ((u >> 16) & 1u)) >> 16;   // RNE
    return (ushort_t)u;
}
__device__ __forceinline__ float ld_any(const void* p, int i, bool f32){
    return f32 ? ((const float*)p)[i] : bf2f(((const ushort_t*)p)[i]);
}
__device__ __forceinline__ float exp2_fast(float x){
#if __has_builtin(__builtin_amdgcn_exp2f)
    return __builtin_amdgcn_exp2f(x);          // v_exp_f32 (2^x)
#else
    return __expf(0.6931471805599453f * x);
#endif
}
__device__ __forceinline__ float rcp_fast(float x){
#if __has_builtin(__builtin_amdgcn_rcpf)
    return __builtin_amdgcn_rcpf(x);           // v_rcp_f32
#else
    return __fdividef(1.0f, x);
#endif
}
// sigma(x) with pre-scaled argument t = log2e * x
__device__ __forceinline__ float sigm2(float t){
    return rcp_fast(1.0f + exp2_fast(-t));
}
// tanh(y) with pre-scaled argument t = 2*log2e * y
__device__ __forceinline__ float tanh2(float t){
    return fmaf(-2.0f, rcp_fast(exp2_fast(t) + 1.0f), 1.0f);
}
__device__ __forceinline__ f32x4 mfma16(bf16x8 a, bf16x8 b, f32x4 c){
    return __builtin_amdgcn_mfma_f32_16x16x32_bf16(a, b, c, 0, 0, 0);
}
// packed f32x2 -> bf16x2 (RNE) in one instruction
__device__ __forceinline__ unsigned int cvtpk(float lo, float hi){
    unsigned int r;
    asm("v_cvt_pk_bf16_f32 %0, %1, %2" : "=v"(r) : "v"(lo), "v"(hi));
    return r;
}
// A-fragment: 8 contiguous k's of W[n][k], pre-scaled then bf16-rounded.
__device__ __forceinline__ bf16x8 mk_frag(const void* W, int n, int kb, bool f32, float sc){
    us8 tmp;
    #pragma unroll
    for (int j = 0; j < 8; ++j){
        float v = f32 ? ((const float*)W)[n * 64 + kb + j]
                      : bf2f(((const ushort_t*)W)[n * 64 + kb + j]);
        tmp[j] = f2bf(v * sc);
    }
    return __builtin_bit_cast(bf16x8, tmp);
}

__global__ __launch_bounds__(512, 2) void gru_fused(
    const void* __restrict__ xv,
    const void* __restrict__ Wih0, const void* __restrict__ Whh0,
    const void* __restrict__ bih0, const void* __restrict__ bhh0,
    const void* __restrict__ Wih1, const void* __restrict__ Whh1,
    const void* __restrict__ bih1, const void* __restrict__ bhh1,
    const void* __restrict__ Wfc,  const void* __restrict__ bfc,
    void* __restrict__ outv)
{
    // h exchange: [parity][group][quarter tau][lane], ui2 = 4 bf16 frag layout
    __shared__ ui2   hAq[2][2][4][64];
    __shared__ ui2   hBq[2][2][4][64];
    __shared__ float fcb[2][4][16];        // FC cross-wave partials per group

    const int tid   = threadIdx.x;
    const int wv    = tid >> 6;            // 0..7
    const int layer = wv >> 2;             // 0 = GRU0 waves, 1 = GRU1 waves
    const int tau   = wv & 3;              // weight tile this wave owns
    const int l  = tid & 63;
    const int b  = l & 15;                 // batch row within group (D column)
    const int hp = l >> 4;                 // k-group (MFMA D row block)
    const int am = l & 15;                 // A-operand row this lane loads
    const long row0 = (long)blockIdx.x * BROWS;

    // dtype detection (uniform): fp32 misread as bf16 -> mantissa-noise
    // exponents in even ushort slots; true bf16 never exceeds exp 150.
    bool f32 = false;
    {
        const ushort_t* xs = (const ushort_t*)xv;
        for (int j = 0; j < 64; ++j){
            int e = (xs[2 * j] >> 7) & 0xFF;
            if (e > 150) f32 = true;
        }
    }

    // zero exchange buffers (h(-1) = 0, h(-2) = 0; both parities)
    {
        ui2 z = {0u, 0u};
        ui2* pa = &hAq[0][0][0][0];
        ui2* pb = &hBq[0][0][0][0];
        for (int k = tid; k < 2 * 2 * 4 * 64; k += 512){ pa[k] = z; pb[k] = z; }
    }

    const float gsc0 = LOG2E, gsc2 = 2.0f * LOG2E;

    // ---- weight / bias setup (per wave role; shared across both groups) ----
    // Permuted gate row for tile tau:
    //   grow(g) = g*64 + 32*(tau>>1) + 8*(am>>2) + 4*(tau&1) + (am&3)
    // Lane's D outputs land at h-col hc(r) = hb0 + r,
    //   hb0 = 32*(tau>>1) + 8*hp + 4*(tau&1)  -- the ui2 quarter published.
    bf16x8 wA[3][2];                       // L0: Whh0. L1: Wih1.
    bf16x8 wH[3][2];                       // L1 only: Whh1.
    f32x4 cbR, cbZ, cbNx, cbNh;
    f32x4 cwR, cwZ, cwN;                   // L0 only: scalar-x weights
    const void* Wihp = layer ? Wih1 : Wih0;
    const void* Whhp = layer ? Whh1 : Whh0;
    const void* bihp = layer ? bih1 : bih0;
    const void* bhhp = layer ? bhh1 : bhh0;
    const int hb0 = 32 * (tau >> 1) + 8 * hp + 4 * (tau & 1);
    #pragma unroll
    for (int g = 0; g < 3; ++g){
        const float sc = (g == 2) ? gsc2 : gsc0;
        const int grow = g * 64 + 32 * (tau >> 1) + 8 * (am >> 2) + 4 * (tau & 1) + (am & 3);
        if (layer == 0){
            wA[g][0] = mk_frag(Whhp, grow, 8 * hp,      f32, sc);
            wA[g][1] = mk_frag(Whhp, grow, 32 + 8 * hp, f32, sc);
        } else {
            wA[g][0] = mk_frag(Wihp, grow, 8 * hp,      f32, sc);
            wA[g][1] = mk_frag(Wihp, grow, 32 + 8 * hp, f32, sc);
            wH[g][0] = mk_frag(Whhp, grow, 8 * hp,      f32, sc);
            wH[g][1] = mk_frag(Whhp, grow, 32 + 8 * hp, f32, sc);
        }
    }
    #pragma unroll
    for (int r = 0; r < 4; ++r){
        const int hc = hb0 + r;
        cbR[r]  = (ld_any(bihp, hc, f32)      + ld_any(bhhp, hc, f32))      * gsc0;
        cbZ[r]  = (ld_any(bihp, 64 + hc, f32) + ld_any(bhhp, 64 + hc, f32)) * gsc0;
        cbNx[r] = ld_any(bihp, 128 + hc, f32) * gsc2;
        cbNh[r] = ld_any(bhhp, 128 + hc, f32) * gsc2;
        if (layer == 0){
            cwR[r] = ld_any(Wih0, hc, f32)       * gsc0;
            cwZ[r] = ld_any(Wih0, 64 + hc, f32)  * gsc0;
            cwN[r] = ld_any(Wih0, 128 + hc, f32) * gsc2;
        }
    }

    f32x4 hS[2] = {{0,0,0,0},{0,0,0,0}};   // f32-carried h, per group

    __syncthreads();                       // barrier #1: init complete

    if (layer == 0){
        // ================= LAYER-0 WAVES =================
        // per-lane x prefetch (x block is L2-resident; hidden under step)
        float xc0 = ld_any(xv, (int)((row0 + b)      * T_LEN), f32);
        float xc1 = ld_any(xv, (int)((row0 + 16 + b) * T_LEN), f32);
        for (int t = 0; t < T_LEN; ++t){
            const int tn = (t + 1 < T_LEN) ? t + 1 : T_LEN - 1;
            float xn0 = ld_any(xv, (int)((row0 + b)      * T_LEN + tn), f32);
            float xn1 = ld_any(xv, (int)((row0 + 16 + b) * T_LEN + tn), f32);
            const int p = t & 1, pr = p ^ 1;
            // issue both groups' exchange reads up front
            ui2 q[2][4];
            #pragma unroll
            for (int g = 0; g < 2; ++g){
                #pragma unroll
                for (int k = 0; k < 4; ++k) q[g][k] = hAq[pr][g][k][l];
            }
            const float xcv[2] = { xc0, xc1 };
            #pragma unroll
            for (int g = 0; g < 2; ++g){
                ui4 u0 = {q[g][0][0], q[g][0][1], q[g][1][0], q[g][1][1]};
                ui4 u1 = {q[g][2][0], q[g][2][1], q[g][3][0], q[g][3][1]};
                bf16x8 B0 = __builtin_bit_cast(bf16x8, u0);   // k 8hp..+7
                bf16x8 B1 = __builtin_bit_cast(bf16x8, u1);   // k 32+8hp..+7
                const float xb = xcv[g];
                f32x4 aR, aZ, aX, aN;
                #pragma unroll
                for (int r = 0; r < 4; ++r){
                    aR[r] = fmaf(xb, cwR[r], cbR[r]);
                    aZ[r] = fmaf(xb, cwZ[r], cbZ[r]);
                    aX[r] = fmaf(xb, cwN[r], cbNx[r]);
                }
                aR = mfma16(wA[0][0], B0, aR); aR = mfma16(wA[0][1], B1, aR);
                aZ = mfma16(wA[1][0], B0, aZ); aZ = mfma16(wA[1][1], B1, aZ);
                aN = mfma16(wA[2][0], B0, cbNh); aN = mfma16(wA[2][1], B1, aN);
                #pragma unroll
                for (int r = 0; r < 4; ++r){
                    float rg = sigm2(aR[r]);
                    float zg = sigm2(aZ[r]);
                    float ng = tanh2(aX[r] + rg * aN[r]);
                    hS[g][r] = ng + zg * (hS[g][r] - ng);
                }
                ui2 own = { cvtpk(hS[g][0], hS[g][1]), cvtpk(hS[g][2], hS[g][3]) };
                hAq[p][g][tau][l] = own;
            }
            xc0 = xn0; xc1 = xn1;
            __syncthreads();               // barriers #2..#513
        }
    } else {
        // ================= LAYER-1 WAVES =================
        // iteration t (t>0) computes hB(t-1); t=0 idles (phase-lock with L0).
        for (int t = 0; t < T_LEN; ++t){
            if (t > 0){
                const int pa = (t - 1) & 1, pb = pa ^ 1;
                ui2 a[2][4], c[2][4];
                #pragma unroll
                for (int g = 0; g < 2; ++g){
                    #pragma unroll
                    for (int k = 0; k < 4; ++k){
                        a[g][k] = hAq[pa][g][k][l];
                        c[g][k] = hBq[pb][g][k][l];
                    }
                }
                #pragma unroll
                for (int g = 0; g < 2; ++g){
                    ui4 ua0 = {a[g][0][0], a[g][0][1], a[g][1][0], a[g][1][1]};
                    ui4 ua1 = {a[g][2][0], a[g][2][1], a[g][3][0], a[g][3][1]};
                    ui4 ub0 = {c[g][0][0], c[g][0][1], c[g][1][0], c[g][1][1]};
                    ui4 ub1 = {c[g][2][0], c[g][2][1], c[g][3][0], c[g][3][1]};
                    bf16x8 gA0 = __builtin_bit_cast(bf16x8, ua0);
                    bf16x8 gA1 = __builtin_bit_cast(bf16x8, ua1);
                    bf16x8 B0  = __builtin_bit_cast(bf16x8, ub0);
                    bf16x8 B1  = __builtin_bit_cast(bf16x8, ub1);
                    f32x4 aR, aZ, aX, aN;
                    aR = mfma16(wA[0][0], gA0, cbR);  aR = mfma16(wA[0][1], gA1, aR);
                    aR = mfma16(wH[0][0], B0,  aR);   aR = mfma16(wH[0][1], B1,  aR);
                    aZ = mfma16(wA[1][0], gA0, cbZ);  aZ = mfma16(wA[1][1], gA1, aZ);
                    aZ = mfma16(wH[1][0], B0,  aZ);   aZ = mfma16(wH[1][1], B1,  aZ);
                    aX = mfma16(wA[2][0], gA0, cbNx); aX = mfma16(wA[2][1], gA1, aX);
                    aN = mfma16(wH[2][0], B0,  cbNh); aN = mfma16(wH[2][1], B1,  aN);
                    #pragma unroll
                    for (int r = 0; r < 4; ++r){
                        float rg = sigm2(aR[r]);
                        float zg = sigm2(aZ[r]);
                        float ng = tanh2(aX[r] + rg * aN[r]);
                        hS[g][r] = ng + zg * (hS[g][r] - ng);
                    }
                    ui2 own = { cvtpk(hS[g][0], hS[g][1]), cvtpk(hS[g][2], hS[g][3]) };
                    hBq[pa][g][tau][l] = own;
                }
            }
            __syncthreads();               // barriers #2..#513
        }
    }

    // Epilogue: L1 waves compute hB(511) from hA(511) (parity 1) and
    // hB(510) (parity 0), then fold the FC dot-product in registers.
    // (L0 finished hA(511) before its last in-loop barrier; no writes here.)
    if (layer == 1){
        ui2 a[2][4], c[2][4];
        #pragma unroll
        for (int g = 0; g < 2; ++g){
            #pragma unroll
            for (int k = 0; k < 4; ++k){
                a[g][k] = hAq[1][g][k][l];
                c[g][k] = hBq[0][g][k][l];
            }
        }
        #pragma unroll
        for (int g = 0; g < 2; ++g){
            ui4 ua0 = {a[g][0][0], a[g][0][1], a[g][1][0], a[g][1][1]};
            ui4 ua1 = {a[g][2][0], a[g][2][1], a[g][3][0], a[g][3][1]};
            ui4 ub0 = {c[g][0][0], c[g][0][1], c[g][1][0], c[g][1][1]};
            ui4 ub1 = {c[g][2][0], c[g][2][1], c[g][3][0], c[g][3][1]};
            bf16x8 gA0 = __builtin_bit_cast(bf16x8, ua0);
            bf16x8 gA1 = __builtin_bit_cast(bf16x8, ua1);
            bf16x8 B0  = __builtin_bit_cast(bf16x8, ub0);
            bf16x8 B1  = __builtin_bit_cast(bf16x8, ub1);
            f32x4 aR, aZ, aX, aN;
            aR = mfma16(wA[0][0], gA0, cbR);  aR = mfma16(wA[0][1], gA1, aR);
            aR = mfma16(wH[0][0], B0,  aR);   aR = mfma16(wH[0][1], B1,  aR);
            aZ = mfma16(wA[1][0], gA0, cbZ);  aZ = mfma16(wA[1][1], gA1, aZ);
            aZ = mfma16(wH[1][0], B0,  aZ);   aZ = mfma16(wH[1][1], B1,  aZ);
            aX = mfma16(wA[2][0], gA0, cbNx); aX = mfma16(wA[2][1], gA1, aX);
            aN = mfma16(wH[2][0], B0,  cbNh); aN = mfma16(wH[2][1], B1,  aN);
            float part = 0.0f;
            #pragma unroll
            for (int r = 0; r < 4; ++r){
                float rg = sigm2(aR[r]);
                float zg = sigm2(aZ[r]);
                float ng = tanh2(aX[r] + rg * aN[r]);
                float hf = ng + zg * (hS[g][r] - ng);
                part = fmaf(ld_any(Wfc, hb0 + r, f32), hf, part);
            }
            part += __shfl_xor(part, 16);      // reduce across hp
            part += __shfl_xor(part, 32);
            if (l < 16) fcb[g][tau][b] = part;
        }
    }

    __syncthreads();                       // barrier #514: fcb ready

    if (tid < 2 * 16){
        const int g = tid >> 4, bb = tid & 15;
        float s = fcb[g][0][bb] + fcb[g][1][bb] + fcb[g][2][bb] + fcb[g][3][bb]
                + ld_any(bfc, 0, f32);
        if (f32) ((float*)outv)[row0 + g * 16 + bb] = s;
        else     ((ushort_t*)outv)[row0 + g * 16 + bb] = f2bf(s);
    }
}

extern "C" void kernel_launch(void* const* d_in, const int* in_sizes, int n_in,
                              void* d_out, int out_size, void* d_ws, size_t ws_size,
                              hipStream_t stream)
{
    (void)in_sizes; (void)n_in; (void)d_ws; (void)ws_size;
    const int B = out_size;               // O = 1 -> out_size == batch
    const int nblk = B / BROWS;           // 2048/32 = 64 blocks, 8 waves each
    gru_fused<<<nblk, 512, 0, stream>>>(
        d_in[0],
        d_in[1], d_in[2], d_in[3], d_in[4],
        d_in[5], d_in[6], d_in[7], d_in[8],
        d_in[9], d_in[10],
        d_out);
}